// Round 3
// baseline (398.861 us; speedup 1.0000x reference)
//
#include <hip/hip_runtime.h>
#include <math.h>

// afm_27805618274715 v3: MEASUREMENT ROUND — identical v2 kernel launched 3x
// back-to-back (idempotent) to extract true kernel time from dur_us:
//   dur = harness_overhead + 3*k   (prev round: overhead + k = 337us)
//   => k = (dur_v3 - 337)/2
// Kernel body is byte-identical to v2 (4 lanes/group, 12 float4 gathers in
// flight, W1+indices in LDS).

static constexpr int G_TOTAL = 262144;
static constexpr int GPB = 64;   // groups per block

__device__ __forceinline__ float sigf(float x) {
    return 1.0f / (1.0f + expf(-x));
}

__global__ __launch_bounds__(256) void afm_kernel(
    const int*   __restrict__ group,   // [G,3]
    const float* __restrict__ embed,   // [1M,64]
    const float* __restrict__ W1,      // [64,4] row-major
    const float* __restrict__ b1,      // [4]
    const float* __restrict__ W2,      // [4]
    const float* __restrict__ b2,      // [1]
    const float* __restrict__ Wp,      // [3]
    const float* __restrict__ bp,      // [1]
    float*       __restrict__ out)     // [G]
{
    __shared__ int    s_idx[GPB * 3];   // 192 ints
    __shared__ float4 s_w1[64];         // W1: one float4 (4 features) per dim

    const int t = threadIdx.x;

    if (t < GPB * 3) s_idx[t] = group[blockIdx.x * (GPB * 3) + t];
    if (t < 64)      s_w1[t] = ((const float4*)W1)[t];
    __syncthreads();

    const int sub = t >> 2;          // group within block (0..63)
    const int l   = t & 3;           // lane within 4-lane subgroup
    const int g   = blockIdx.x * GPB + sub;

    const int i0 = s_idx[sub * 3 + 0];
    const int i1 = s_idx[sub * 3 + 1];
    const int i2 = s_idx[sub * 3 + 2];

    const float4* p0 = (const float4*)(embed + (size_t)i0 * 64);
    const float4* p1 = (const float4*)(embed + (size_t)i1 * 64);
    const float4* p2 = (const float4*)(embed + (size_t)i2 * 64);

    float4 e0[4], e1[4], e2[4];
#pragma unroll
    for (int j = 0; j < 4; ++j) {
        e0[j] = p0[j * 4 + l];
        e1[j] = p1[j * 4 + l];
        e2[j] = p2[j * 4 + l];
    }

    float4 acc01 = {0,0,0,0}, acc02 = {0,0,0,0}, acc12 = {0,0,0,0};
#pragma unroll
    for (int j = 0; j < 4; ++j) {
        const float4 a = e0[j], b = e1[j], c = e2[j];
        const float v01[4] = {a.x*b.x, a.y*b.y, a.z*b.z, a.w*b.w};
        const float v02[4] = {a.x*c.x, a.y*c.y, a.z*c.z, a.w*c.w};
        const float v12[4] = {b.x*c.x, b.y*c.y, b.z*c.z, b.w*c.w};
#pragma unroll
        for (int k = 0; k < 4; ++k) {
            const float4 w = s_w1[j * 16 + l * 4 + k];  // dim = 4*(4j+l)+k
            acc01.x = fmaf(v01[k], w.x, acc01.x);
            acc01.y = fmaf(v01[k], w.y, acc01.y);
            acc01.z = fmaf(v01[k], w.z, acc01.z);
            acc01.w = fmaf(v01[k], w.w, acc01.w);
            acc02.x = fmaf(v02[k], w.x, acc02.x);
            acc02.y = fmaf(v02[k], w.y, acc02.y);
            acc02.z = fmaf(v02[k], w.z, acc02.z);
            acc02.w = fmaf(v02[k], w.w, acc02.w);
            acc12.x = fmaf(v12[k], w.x, acc12.x);
            acc12.y = fmaf(v12[k], w.y, acc12.y);
            acc12.z = fmaf(v12[k], w.z, acc12.z);
            acc12.w = fmaf(v12[k], w.w, acc12.w);
        }
    }

#pragma unroll
    for (int m = 2; m >= 1; m >>= 1) {
        acc01.x += __shfl_xor(acc01.x, m);
        acc01.y += __shfl_xor(acc01.y, m);
        acc01.z += __shfl_xor(acc01.z, m);
        acc01.w += __shfl_xor(acc01.w, m);
        acc02.x += __shfl_xor(acc02.x, m);
        acc02.y += __shfl_xor(acc02.y, m);
        acc02.z += __shfl_xor(acc02.z, m);
        acc02.w += __shfl_xor(acc02.w, m);
        acc12.x += __shfl_xor(acc12.x, m);
        acc12.y += __shfl_xor(acc12.y, m);
        acc12.z += __shfl_xor(acc12.z, m);
        acc12.w += __shfl_xor(acc12.w, m);
    }

    const float b10 = b1[0], b11 = b1[1], b12v = b1[2], b13 = b1[3];
    const float w20 = W2[0], w21 = W2[1], w22 = W2[2], w23 = W2[3];
    const float b2v = b2[0];

    const float a0 = b2v + sigf(acc01.x + b10) * w20 + sigf(acc01.y + b11) * w21
                         + sigf(acc01.z + b12v) * w22 + sigf(acc01.w + b13) * w23;
    const float a1 = b2v + sigf(acc02.x + b10) * w20 + sigf(acc02.y + b11) * w21
                         + sigf(acc02.z + b12v) * w22 + sigf(acc02.w + b13) * w23;
    const float a2 = b2v + sigf(acc12.x + b10) * w20 + sigf(acc12.y + b11) * w21
                         + sigf(acc12.z + b12v) * w22 + sigf(acc12.w + b13) * w23;

    const float z = bp[0] + a0 * Wp[0] + a1 * Wp[1] + a2 * Wp[2];
    const float res = 2.0f / (1.0f + expf(-z)) - 1.0f;

    if (l == 0) out[g] = res;
}

extern "C" void kernel_launch(void* const* d_in, const int* in_sizes, int n_in,
                              void* d_out, int out_size, void* d_ws, size_t ws_size,
                              hipStream_t stream) {
    const int*   group = (const int*)  d_in[0];
    const float* embed = (const float*)d_in[1];
    const float* W1    = (const float*)d_in[2];
    const float* b1    = (const float*)d_in[3];
    const float* W2    = (const float*)d_in[4];
    const float* b2    = (const float*)d_in[5];
    const float* Wp    = (const float*)d_in[6];
    const float* bp    = (const float*)d_in[7];
    float* out = (float*)d_out;

    // MEASUREMENT: 3 identical idempotent launches. k = (dur - 337us)/2.
    for (int rep = 0; rep < 3; ++rep) {
        afm_kernel<<<G_TOTAL / GPB, 256, 0, stream>>>(
            group, embed, W1, b1, W2, b2, Wp, bp, out);
    }
}

// Round 4
// 335.559 us; speedup vs baseline: 1.1886x; 1.1886x over previous
//
#include <hip/hip_runtime.h>
#include <math.h>

// afm_27805618274715 v4: revert to single launch of the v2 kernel.
// MEASURED (R3, 3x-launch probe): kernel time k ~= 31 us per launch.
// Roofline: 262144 groups x 3 rows x 256 B = 192 MB mandatory gather
// (+3 MB idx, +1 MB out) / 6.3 TB/s achievable = 31.1 us -> ~100% of
// the memory roofline. dur_us ~= 337 is dominated by ~306 us of fixed
// harness overhead (1 GB ws poison + input restore), not kernel time.
// Structure: 4 lanes/group (lane owns 16 of 64 dims), 16 groups/wave,
// 12 independent float4 gathers in flight, W1 + indices staged in LDS.

static constexpr int G_TOTAL = 262144;
static constexpr int GPB = 64;   // groups per block

__device__ __forceinline__ float sigf(float x) {
    return 1.0f / (1.0f + expf(-x));
}

__global__ __launch_bounds__(256) void afm_kernel(
    const int*   __restrict__ group,   // [G,3]
    const float* __restrict__ embed,   // [1M,64]
    const float* __restrict__ W1,      // [64,4] row-major
    const float* __restrict__ b1,      // [4]
    const float* __restrict__ W2,      // [4]
    const float* __restrict__ b2,      // [1]
    const float* __restrict__ Wp,      // [3]
    const float* __restrict__ bp,      // [1]
    float*       __restrict__ out)     // [G]
{
    __shared__ int    s_idx[GPB * 3];   // 192 ints
    __shared__ float4 s_w1[64];         // W1: one float4 (4 features) per dim

    const int t = threadIdx.x;

    if (t < GPB * 3) s_idx[t] = group[blockIdx.x * (GPB * 3) + t];
    if (t < 64)      s_w1[t] = ((const float4*)W1)[t];
    __syncthreads();

    const int sub = t >> 2;          // group within block (0..63)
    const int l   = t & 3;           // lane within 4-lane subgroup
    const int g   = blockIdx.x * GPB + sub;

    const int i0 = s_idx[sub * 3 + 0];
    const int i1 = s_idx[sub * 3 + 1];
    const int i2 = s_idx[sub * 3 + 2];

    const float4* p0 = (const float4*)(embed + (size_t)i0 * 64);
    const float4* p1 = (const float4*)(embed + (size_t)i1 * 64);
    const float4* p2 = (const float4*)(embed + (size_t)i2 * 64);

    float4 e0[4], e1[4], e2[4];
#pragma unroll
    for (int j = 0; j < 4; ++j) {
        e0[j] = p0[j * 4 + l];
        e1[j] = p1[j * 4 + l];
        e2[j] = p2[j * 4 + l];
    }

    float4 acc01 = {0,0,0,0}, acc02 = {0,0,0,0}, acc12 = {0,0,0,0};
#pragma unroll
    for (int j = 0; j < 4; ++j) {
        const float4 a = e0[j], b = e1[j], c = e2[j];
        const float v01[4] = {a.x*b.x, a.y*b.y, a.z*b.z, a.w*b.w};
        const float v02[4] = {a.x*c.x, a.y*c.y, a.z*c.z, a.w*c.w};
        const float v12[4] = {b.x*c.x, b.y*c.y, b.z*c.z, b.w*c.w};
#pragma unroll
        for (int k = 0; k < 4; ++k) {
            const float4 w = s_w1[j * 16 + l * 4 + k];  // dim = 4*(4j+l)+k
            acc01.x = fmaf(v01[k], w.x, acc01.x);
            acc01.y = fmaf(v01[k], w.y, acc01.y);
            acc01.z = fmaf(v01[k], w.z, acc01.z);
            acc01.w = fmaf(v01[k], w.w, acc01.w);
            acc02.x = fmaf(v02[k], w.x, acc02.x);
            acc02.y = fmaf(v02[k], w.y, acc02.y);
            acc02.z = fmaf(v02[k], w.z, acc02.z);
            acc02.w = fmaf(v02[k], w.w, acc02.w);
            acc12.x = fmaf(v12[k], w.x, acc12.x);
            acc12.y = fmaf(v12[k], w.y, acc12.y);
            acc12.z = fmaf(v12[k], w.z, acc12.z);
            acc12.w = fmaf(v12[k], w.w, acc12.w);
        }
    }

#pragma unroll
    for (int m = 2; m >= 1; m >>= 1) {
        acc01.x += __shfl_xor(acc01.x, m);
        acc01.y += __shfl_xor(acc01.y, m);
        acc01.z += __shfl_xor(acc01.z, m);
        acc01.w += __shfl_xor(acc01.w, m);
        acc02.x += __shfl_xor(acc02.x, m);
        acc02.y += __shfl_xor(acc02.y, m);
        acc02.z += __shfl_xor(acc02.z, m);
        acc02.w += __shfl_xor(acc02.w, m);
        acc12.x += __shfl_xor(acc12.x, m);
        acc12.y += __shfl_xor(acc12.y, m);
        acc12.z += __shfl_xor(acc12.z, m);
        acc12.w += __shfl_xor(acc12.w, m);
    }

    const float b10 = b1[0], b11 = b1[1], b12v = b1[2], b13 = b1[3];
    const float w20 = W2[0], w21 = W2[1], w22 = W2[2], w23 = W2[3];
    const float b2v = b2[0];

    const float a0 = b2v + sigf(acc01.x + b10) * w20 + sigf(acc01.y + b11) * w21
                         + sigf(acc01.z + b12v) * w22 + sigf(acc01.w + b13) * w23;
    const float a1 = b2v + sigf(acc02.x + b10) * w20 + sigf(acc02.y + b11) * w21
                         + sigf(acc02.z + b12v) * w22 + sigf(acc02.w + b13) * w23;
    const float a2 = b2v + sigf(acc12.x + b10) * w20 + sigf(acc12.y + b11) * w21
                         + sigf(acc12.z + b12v) * w22 + sigf(acc12.w + b13) * w23;

    const float z = bp[0] + a0 * Wp[0] + a1 * Wp[1] + a2 * Wp[2];
    const float res = 2.0f / (1.0f + expf(-z)) - 1.0f;

    if (l == 0) out[g] = res;
}

extern "C" void kernel_launch(void* const* d_in, const int* in_sizes, int n_in,
                              void* d_out, int out_size, void* d_ws, size_t ws_size,
                              hipStream_t stream) {
    const int*   group = (const int*)  d_in[0];
    const float* embed = (const float*)d_in[1];
    const float* W1    = (const float*)d_in[2];
    const float* b1    = (const float*)d_in[3];
    const float* W2    = (const float*)d_in[4];
    const float* b2    = (const float*)d_in[5];
    const float* Wp    = (const float*)d_in[6];
    const float* bp    = (const float*)d_in[7];
    float* out = (float*)d_out;

    afm_kernel<<<G_TOTAL / GPB, 256, 0, stream>>>(
        group, embed, W1, b1, W2, b2, Wp, bp, out);
}